// Round 2
// baseline (1618.083 us; speedup 1.0000x reference)
//
#include <hip/hip_runtime.h>
#include <hip/hip_bf16.h>

// ---- problem constants (match reference) ----
#define NP 100000
#define NA 50000
#define NTOT 150000          // NP+NA
#define E0 300000
#define E1 300000
#define E2 200000
#define ETOT 800000
#define NH 4
#define HD 16
#define HID 64
#define IN_DIM 128
#define KQV 192
#define LAYERS 2
#define NSRC 250000          // NA + 2*NP

// ---- helpers ----
__device__ __forceinline__ float gelu_exact(float x) {
    return 0.5f * x * (1.0f + erff(x * 0.7071067811865475f));
}
// order-preserving float<->uint encoding for atomicMax
__device__ __forceinline__ unsigned enc_f32(float f) {
    unsigned u = __float_as_uint(f);
    return (u & 0x80000000u) ? ~u : (u | 0x80000000u);
}
__device__ __forceinline__ float dec_f32(unsigned e) {
    unsigned u = (e & 0x80000000u) ? (e ^ 0x80000000u) : ~e;
    return __uint_as_float(u);
}
#define ENC_NEG_INF 0x007FFFFFu   // enc_f32(-inf)

// ---- kernels ----

// h[node] = x[node] @ W + b   (IN_DIM -> HID), 4 nodes / 256-thread block
__global__ void lin_in_kernel(const float* __restrict__ x, const float* __restrict__ W,
                              const float* __restrict__ b, float* __restrict__ hout,
                              int count) {
    int ln   = threadIdx.x >> 6;
    int t    = threadIdx.x & 63;
    int node = blockIdx.x * 4 + ln;
    __shared__ float xs[4][IN_DIM];
    if (node < count) {
        xs[ln][t]      = x[(long)node * IN_DIM + t];
        xs[ln][t + 64] = x[(long)node * IN_DIM + t + 64];
    }
    __syncthreads();
    if (node < count) {
        float acc = b[t];
        #pragma unroll 8
        for (int i = 0; i < IN_DIM; i++) acc += xs[ln][i] * W[i * HID + t];
        hout[(long)node * HID + t] = acc;
    }
}

// init m_enc=-inf, s=0
__global__ void init_ms_kernel(unsigned* __restrict__ m_enc, float* __restrict__ s, int nm) {
    int i = blockIdx.x * blockDim.x + threadIdx.x;
    int stride = gridDim.x * blockDim.x;
    for (int j = i; j < nm; j += stride) { m_enc[j] = ENC_NEG_INF; s[j] = 0.0f; }
}

// zero attn accumulator (runs AFTER alpha_max; attn aliases Q)
__global__ void zero_attn_kernel(float* __restrict__ attn, int n) {
    int i = blockIdx.x * blockDim.x + threadIdx.x;
    int stride = gridDim.x * blockDim.x;
    for (int j = i; j < n; j += stride) attn[j] = 0.0f;
}

// fused per-node KQV projection + per-edge-type relation transforms.
// 8 nodes per 256-thread block. Writes Q[NTOT,64], Ks[NSRC,64], Vs[NSRC,64].
__global__ void kqv_rel_kernel(const float* __restrict__ hbuf,
                               const float* __restrict__ W_kqv, const float* __restrict__ b_kqv,
                               const float* __restrict__ W_krel, const float* __restrict__ W_vrel,
                               float* __restrict__ Q, float* __restrict__ Ks,
                               float* __restrict__ Vs) {
    int n0 = blockIdx.x * 8;
    int t  = threadIdx.x;
    __shared__ float hs[8][HID];
    __shared__ float kqvs[8][KQV];
    #pragma unroll
    for (int r = 0; r < 2; r++) {
        int idx = r * 256 + t;           // 0..511
        int nl = idx >> 6, c = idx & 63;
        int n = n0 + nl;
        if (n < NTOT) hs[nl][c] = hbuf[(long)n * HID + c];
    }
    __syncthreads();
    #pragma unroll
    for (int r = 0; r < 6; r++) {
        int idx = r * 256 + t;           // 0..1535
        int nl = idx / KQV, j = idx % KQV;
        int n = n0 + nl;
        if (n < NTOT) {
            int type = (n < NP) ? 0 : 1;
            const float* W = W_kqv + (size_t)type * HID * KQV;
            float acc = b_kqv[type * KQV + j];
            #pragma unroll 8
            for (int i = 0; i < HID; i++) acc += hs[nl][i] * W[i * KQV + j];
            kqvs[nl][j] = acc;
            if (j >= 64 && j < 128) Q[(long)n * HID + (j - 64)] = acc;
        }
    }
    __syncthreads();
    // relation transforms: paper -> (k,v) x (et1,et2); author -> (k,v) x et0
    #pragma unroll
    for (int r = 0; r < 8; r++) {
        int idx = r * 256 + t;           // 0..2047
        int nl = idx >> 8, w = idx & 255;
        int n = n0 + nl;
        if (n >= NTOT) continue;
        int which = w >> 6;              // 0..3
        int idx2 = w & 63;
        int hh = idx2 >> 4, e = idx2 & 15;
        if (n < NP) {
            int et = (which & 1) ? 2 : 1;
            bool isV = (which >= 2);
            const float* srcv = &kqvs[nl][(isV ? 128 : 0) + hh * HD];
            const float* Wr = (isV ? W_vrel : W_krel) + (size_t)(et * NH + hh) * HD * HD;
            float acc = 0.0f;
            #pragma unroll
            for (int d = 0; d < HD; d++) acc += srcv[d] * Wr[d * HD + e];
            long out_n = (et == 1) ? (long)(NA + n) : (long)(NA + NP + n);
            (isV ? Vs : Ks)[out_n * HID + idx2] = acc;
        } else {
            if (which >= 2) continue;
            bool isV = (which == 1);
            const float* srcv = &kqvs[nl][(isV ? 128 : 0) + hh * HD];
            const float* Wr = (isV ? W_vrel : W_krel) + (size_t)hh * HD * HD;  // et0
            float acc = 0.0f;
            #pragma unroll
            for (int d = 0; d < HD; d++) acc += srcv[d] * Wr[d * HD + e];
            (isV ? Vs : Ks)[(long)(n - NP) * HID + idx2] = acc;
        }
    }
}

// decode global edge id -> (src in Ks/Vs space, dst in node space, edge type)
__device__ __forceinline__ void edge_decode(int e, const int* __restrict__ ei_ap,
                                            const int* __restrict__ ei_pa,
                                            const int* __restrict__ ei_pp,
                                            int& src, int& dst, int& et) {
    if (e < E0)            { et = 0; src = ei_ap[e];                  dst = ei_ap[E0 + e]; }
    else if (e < E0 + E1)  { et = 1; int le = e - E0;
                             src = NA + ei_pa[le];                    dst = NP + ei_pa[E1 + le]; }
    else                   { et = 2; int le = e - E0 - E1;
                             src = NA + NP + ei_pp[le];               dst = ei_pp[E2 + le]; }
}

// pass A: logits + segment max (one thread per (edge, head))
__global__ void alpha_max_kernel(const int* __restrict__ ei_ap, const int* __restrict__ ei_pa,
                                 const int* __restrict__ ei_pp,
                                 const float* __restrict__ Q, const float* __restrict__ Ks,
                                 const float* __restrict__ p_rel,
                                 float* __restrict__ alpha, unsigned* __restrict__ m_enc) {
    int tid = blockIdx.x * blockDim.x + threadIdx.x;
    if (tid >= ETOT * NH) return;
    int e = tid >> 2, hh = tid & 3;
    int src, dst, et;
    edge_decode(e, ei_ap, ei_pa, ei_pp, src, dst, et);
    const float* q = Q + (long)dst * HID + hh * HD;
    const float* k = Ks + (long)src * HID + hh * HD;
    float acc = 0.0f;
    #pragma unroll
    for (int d = 0; d < HD; d++) acc += q[d] * k[d];
    acc *= p_rel[et * NH + hh] * 0.25f;   // 1/sqrt(16)
    alpha[tid] = acc;
    atomicMax(m_enc + dst * NH + hh, enc_f32(acc));
}

// pass B: p = exp(logit - m); s += p; attn[dst] += p * Vs[src]  (one thread per (edge, dim))
__global__ void exp_scatter_kernel(const int* __restrict__ ei_ap, const int* __restrict__ ei_pa,
                                   const int* __restrict__ ei_pp,
                                   const float* __restrict__ Vs, const float* __restrict__ alpha,
                                   const unsigned* __restrict__ m_enc,
                                   float* __restrict__ s, float* __restrict__ attn) {
    long tid = (long)blockIdx.x * blockDim.x + threadIdx.x;
    if (tid >= (long)ETOT * HID) return;
    int e = (int)(tid >> 6);
    int idx = (int)(tid & 63);
    int hh = idx >> 4;
    int src, dst, et;
    edge_decode(e, ei_ap, ei_pa, ei_pp, src, dst, et);
    float m = dec_f32(m_enc[dst * NH + hh]);
    float p = expf(alpha[e * NH + hh] - m);
    if ((idx & 15) == 0) atomicAdd(s + dst * NH + hh, p);
    atomicAdd(attn + (long)dst * HID + idx, p * Vs[(long)src * HID + idx]);
}

// normalize + gelu + W_hout + sigmoid-skip residual into h (4 nodes / block)
__global__ void hout_skip_kernel(const float* __restrict__ attn, const float* __restrict__ s,
                                 const float* __restrict__ W_hout, const float* __restrict__ b_hout,
                                 const float* __restrict__ skip_p,
                                 float* __restrict__ hbuf, int base, int count) {
    int ln   = threadIdx.x >> 6;
    int t    = threadIdx.x & 63;
    int node = blockIdx.x * 4 + ln;
    __shared__ float gs[4][HID];
    if (node < count) {
        int n = base + node;
        float sv = s[n * NH + (t >> 4)];
        float val = attn[(long)n * HID + t] / (sv + 1e-16f);
        gs[ln][t] = gelu_exact(val);
    }
    __syncthreads();
    if (node < count) {
        int n = base + node;
        float acc = b_hout[t];
        #pragma unroll 8
        for (int i = 0; i < HID; i++) acc += gs[ln][i] * W_hout[i * HID + t];
        float a = 1.0f / (1.0f + expf(-skip_p[0]));
        float hold = hbuf[(long)n * HID + t];
        hbuf[(long)n * HID + t] = a * acc + (1.0f - a) * hold;
    }
}

// h = gelu(layernorm(h)) , one wave per node
__global__ void ln_gelu_kernel(float* __restrict__ hbuf, const float* __restrict__ g,
                               const float* __restrict__ b, int base, int count) {
    int node = blockIdx.x * 4 + (threadIdx.x >> 6);
    int t = threadIdx.x & 63;
    if (node >= count) return;
    long off = (long)(base + node) * HID;
    float x = hbuf[off + t];
    float sum = x;
    #pragma unroll
    for (int o = 32; o > 0; o >>= 1) sum += __shfl_xor(sum, o, 64);
    float mean = sum * (1.0f / 64.0f);
    float d = x - mean;
    float vs = d * d;
    #pragma unroll
    for (int o = 32; o > 0; o >>= 1) vs += __shfl_xor(vs, o, 64);
    float var = vs * (1.0f / 64.0f);
    float y = d * rsqrtf(var + 1e-5f) * g[t] + b[t];
    hbuf[off + t] = gelu_exact(y);
}

// final per-type linear -> f32 output (reference output dtype is float32)
__global__ void out_kernel(const float* __restrict__ hbuf, const float* __restrict__ W,
                           const float* __restrict__ b, float* __restrict__ out,
                           int base, int count) {
    int ln   = threadIdx.x >> 6;
    int t    = threadIdx.x & 63;
    int node = blockIdx.x * 4 + ln;
    __shared__ float hsh[4][HID];
    if (node < count) hsh[ln][t] = hbuf[(long)(base + node) * HID + t];
    __syncthreads();
    if (node < count) {
        float acc = b[t];
        #pragma unroll 8
        for (int i = 0; i < HID; i++) acc += hsh[ln][i] * W[i * HID + t];
        out[(long)(base + node) * HID + t] = acc;
    }
}

extern "C" void kernel_launch(void* const* d_in, const int* in_sizes, int n_in,
                              void* d_out, int out_size, void* d_ws, size_t ws_size,
                              hipStream_t stream) {
    const float* x_paper  = (const float*)d_in[0];
    const float* x_author = (const float*)d_in[1];
    const int*   ei_ap    = (const int*)d_in[2];
    const int*   ei_pa    = (const int*)d_in[3];
    const int*   ei_pp    = (const int*)d_in[4];
    const float* W_in     = (const float*)d_in[5];
    const float* b_in     = (const float*)d_in[6];
    const float* W_kqv    = (const float*)d_in[7];
    const float* b_kqv    = (const float*)d_in[8];
    const float* W_krel   = (const float*)d_in[9];
    const float* W_vrel   = (const float*)d_in[10];
    const float* p_rel    = (const float*)d_in[11];
    const float* W_hout   = (const float*)d_in[12];
    const float* b_hout   = (const float*)d_in[13];
    const float* skip     = (const float*)d_in[14];
    const float* ln_g     = (const float*)d_in[15];
    const float* ln_b     = (const float*)d_in[16];
    const float* W_out    = (const float*)d_in[17];
    const float* b_out    = (const float*)d_in[18];
    float* out            = (float*)d_out;

    // workspace layout (f32), total ~222 MB (attn aliases Q — Q dead after alpha_max)
    float* ws    = (float*)d_ws;
    float* hbuf  = ws;                                  // NTOT*64  f32
    float* Q     = hbuf  + (size_t)NTOT * HID;          // NTOT*64  f32 (also attn)
    float* Ks    = Q     + (size_t)NTOT * HID;          // NSRC*64  f32
    float* Vs    = Ks    + (size_t)NSRC * HID;          // NSRC*64  f32
    float* alpha = Vs    + (size_t)NSRC * HID;          // ETOT*4   f32
    unsigned* m_enc = (unsigned*)(alpha + (size_t)ETOT * NH); // NTOT*4 u32
    float* s     = (float*)(m_enc + (size_t)NTOT * NH); // NTOT*4   f32
    float* attn  = Q;                                   // alias

    dim3 blk(256);

    lin_in_kernel<<<(NP + 3) / 4, blk, 0, stream>>>(x_paper, W_in, b_in, hbuf, NP);
    lin_in_kernel<<<(NA + 3) / 4, blk, 0, stream>>>(x_author, W_in + IN_DIM * HID,
                                                    b_in + HID, hbuf + (size_t)NP * HID, NA);

    for (int l = 0; l < LAYERS; l++) {
        kqv_rel_kernel<<<(NTOT + 7) / 8, blk, 0, stream>>>(
            hbuf,
            W_kqv + (size_t)l * 2 * HID * KQV, b_kqv + (size_t)l * 2 * KQV,
            W_krel + (size_t)l * 3 * NH * HD * HD, W_vrel + (size_t)l * 3 * NH * HD * HD,
            Q, Ks, Vs);
        init_ms_kernel<<<256, blk, 0, stream>>>(m_enc, s, NTOT * NH);
        alpha_max_kernel<<<(ETOT * NH + 255) / 256, blk, 0, stream>>>(
            ei_ap, ei_pa, ei_pp, Q, Ks, p_rel + l * 3 * NH, alpha, m_enc);
        zero_attn_kernel<<<1024, blk, 0, stream>>>(attn, NTOT * HID);   // attn aliases Q
        exp_scatter_kernel<<<(int)(((long)ETOT * HID + 255) / 256), blk, 0, stream>>>(
            ei_ap, ei_pa, ei_pp, Vs, alpha, m_enc, s, attn);
        hout_skip_kernel<<<(NP + 3) / 4, blk, 0, stream>>>(
            attn, s, W_hout + (size_t)(l * 2 + 0) * HID * HID, b_hout + (l * 2 + 0) * HID,
            skip + l * 2 + 0, hbuf, 0, NP);
        hout_skip_kernel<<<(NA + 3) / 4, blk, 0, stream>>>(
            attn, s, W_hout + (size_t)(l * 2 + 1) * HID * HID, b_hout + (l * 2 + 1) * HID,
            skip + l * 2 + 1, hbuf, NP, NA);
        ln_gelu_kernel<<<(NP + 3) / 4, blk, 0, stream>>>(
            hbuf, ln_g + (l * 2 + 0) * HID, ln_b + (l * 2 + 0) * HID, 0, NP);
        ln_gelu_kernel<<<(NA + 3) / 4, blk, 0, stream>>>(
            hbuf, ln_g + (l * 2 + 1) * HID, ln_b + (l * 2 + 1) * HID, NP, NA);
    }

    out_kernel<<<(NP + 3) / 4, blk, 0, stream>>>(hbuf, W_out, b_out, out, 0, NP);
    out_kernel<<<(NA + 3) / 4, blk, 0, stream>>>(hbuf, W_out + HID * HID, b_out + HID,
                                                 out, NP, NA);
}

// Round 3
// 1091.441 us; speedup vs baseline: 1.4825x; 1.4825x over previous
//
#include <hip/hip_runtime.h>
#include <hip/hip_bf16.h>

// ---- problem constants (match reference) ----
#define NP 100000
#define NA 50000
#define NTOT 150000          // NP+NA
#define E0 300000
#define E1 300000
#define E2 200000
#define ETOT 800000
#define NH 4
#define HD 16
#define HID 64
#define IN_DIM 128
#define KQV 192
#define LAYERS 2
#define NSRC 250000          // NA + 2*NP
#define JP 320               // fused paper cols: q | k_et1 | k_et2 | v_et1 | v_et2
#define JA 192               // fused author cols: q | k_et0 | v_et0
#define NCH 586              // ceil(NTOT/256)

__device__ __forceinline__ float gelu_exact(float x) {
    return 0.5f * x * (1.0f + erff(x * 0.7071067811865475f));
}

// decode global edge id -> (src in Ks/Vs space, dst in node space)
__device__ __forceinline__ void edge_decode(int e, const int* __restrict__ ei_ap,
                                            const int* __restrict__ ei_pa,
                                            const int* __restrict__ ei_pp,
                                            int& src, int& dst) {
    if (e < E0)            { src = ei_ap[e];                 dst = ei_ap[E0 + e]; }
    else if (e < E0 + E1)  { int le = e - E0;
                             src = NA + ei_pa[le];           dst = NP + ei_pa[E1 + le]; }
    else                   { int le = e - E0 - E1;
                             src = NA + NP + ei_pp[le];      dst = ei_pp[E2 + le]; }
}

// ---------------- CSR build ----------------
__global__ void zero_int_kernel(int* __restrict__ p, int n) {
    int i = blockIdx.x * blockDim.x + threadIdx.x;
    int st = gridDim.x * blockDim.x;
    for (int j = i; j < n; j += st) p[j] = 0;
}

__global__ void csr_count_kernel(const int* __restrict__ ei_ap, const int* __restrict__ ei_pa,
                                 const int* __restrict__ ei_pp, int* __restrict__ cnt) {
    int e = blockIdx.x * 256 + threadIdx.x;
    if (e >= ETOT) return;
    int src, dst; edge_decode(e, ei_ap, ei_pa, ei_pp, src, dst);
    atomicAdd(&cnt[dst], 1);
}

__global__ void scan_chunk_sums(const int* __restrict__ cnt, int* __restrict__ csum) {
    __shared__ int sd[256];
    int c = blockIdx.x, t = threadIdx.x;
    int i = c * 256 + t;
    sd[t] = (i < NTOT) ? cnt[i] : 0;
    __syncthreads();
    for (int o = 128; o > 0; o >>= 1) { if (t < o) sd[t] += sd[t + o]; __syncthreads(); }
    if (t == 0) csum[c] = sd[0];
}

__global__ void scan_offsets(const int* __restrict__ csum, int* __restrict__ coff, int nch) {
    __shared__ int sd[1024];
    int t = threadIdx.x;
    int v = (t < nch) ? csum[t] : 0;
    sd[t] = v;
    __syncthreads();
    for (int o = 1; o < 1024; o <<= 1) {
        int x = (t >= o) ? sd[t - o] : 0;
        __syncthreads();
        sd[t] += x;
        __syncthreads();
    }
    if (t < nch) coff[t] = sd[t] - v;   // exclusive
}

__global__ void scan_final(const int* __restrict__ cnt, const int* __restrict__ coff,
                           int* __restrict__ row_ptr, int* __restrict__ cursor) {
    __shared__ int sd[256];
    int c = blockIdx.x, t = threadIdx.x, i = c * 256 + t;
    int v = (i < NTOT) ? cnt[i] : 0;
    sd[t] = v;
    __syncthreads();
    for (int o = 1; o < 256; o <<= 1) {
        int x = (t >= o) ? sd[t - o] : 0;
        __syncthreads();
        sd[t] += x;
        __syncthreads();
    }
    if (i < NTOT) { int ex = coff[c] + sd[t] - v; row_ptr[i] = ex; cursor[i] = ex; }
    if (i == 0) row_ptr[NTOT] = ETOT;
}

__global__ void csr_fill_kernel(const int* __restrict__ ei_ap, const int* __restrict__ ei_pa,
                                const int* __restrict__ ei_pp, int* __restrict__ cursor,
                                int* __restrict__ edge_src) {
    int e = blockIdx.x * 256 + threadIdx.x;
    if (e >= ETOT) return;
    int src, dst; edge_decode(e, ei_ap, ei_pa, ei_pp, src, dst);
    int pos = atomicAdd(&cursor[dst], 1);
    edge_src[pos] = src;
}

// ---------------- fused-weight build (per layer) ----------------
// Wfp[64][320], bfp[320]: q | k@rel1 | k@rel2 | v@rel1 | v@rel2   (papers)
// Wfa[64][192], bfa[192]: q | k@rel0 | v@rel0                     (authors)
__global__ void fuse_weights_kernel(const float* __restrict__ Wkqv, const float* __restrict__ bkqv,
                                    const float* __restrict__ Wkrel, const float* __restrict__ Wvrel,
                                    float* __restrict__ Wfp, float* __restrict__ bfp,
                                    float* __restrict__ Wfa, float* __restrict__ bfa) {
    int idx = blockIdx.x * 256 + threadIdx.x;
    int type, i, j;
    if (idx < 65 * JP) { type = 0; i = idx / JP; j = idx % JP; }
    else {
        int r = idx - 65 * JP;
        if (r >= 65 * JA) return;
        type = 1; i = r / JA; j = r % JA;
    }
    int c = j >> 6, jj = j & 63, h = jj >> 4, e = jj & 15;
    const float* Wk = Wkqv + (size_t)type * HID * KQV;
    const float* bk = bkqv + type * KQV;
    float val;
    if (c == 0) {
        val = (i < 64) ? Wk[i * KQV + 64 + jj] : bk[64 + jj];
    } else {
        int et, isV;
        if (type == 0) { et = (c == 1 || c == 3) ? 1 : 2; isV = (c >= 3); }
        else           { et = 0; isV = (c == 2); }
        const float* Wr = (isV ? Wvrel : Wkrel) + (size_t)(et * NH + h) * HD * HD;
        int sb = (isV ? 128 : 0) + h * HD;
        val = 0.0f;
        #pragma unroll
        for (int d = 0; d < HD; d++) {
            float a = (i < 64) ? Wk[i * KQV + sb + d] : bk[sb + d];
            val += a * Wr[d * HD + e];
        }
    }
    if (i < 64) (type ? Wfa : Wfp)[i * (type ? JA : JP) + j] = val;
    else        (type ? bfa : bfp)[j] = val;
}

// ---------------- register-tiled GEMM ----------------
// X:[N][KK] @ W:[KK][ldw], 64-node x 64-col tiles, thread tile 4x4.
// modes: 0 = paper kqv scatter, 1 = author kqv scatter, 2 = hout (gelu-pre + skip), 3 = plain
template<int KK>
__global__ __launch_bounds__(256) void gemm_rt(
    const float* __restrict__ X, int N,
    const float* __restrict__ W, const float* __restrict__ bias,
    int ldw, int nchunks, int mode,
    float* __restrict__ o0, float* __restrict__ o1, float* __restrict__ o2,
    const float* __restrict__ hres, const float* __restrict__ skip_ptr)
{
    __shared__ float xs[64][KK + 4];
    __shared__ float wsb[64][68];
    const int tid = threadIdx.x;
    const int nb  = blockIdx.x * 64;
    const bool pregelu = (mode == 2);

    // stage X tile [64][KK]
    constexpr int F4PR = KK / 4;            // float4 per row
    #pragma unroll
    for (int r = 0; r < KK / 16; r++) {
        int f = tid + 256 * r;
        int row = f / F4PR, col = (f % F4PR) * 4;
        int n = nb + row;
        float4 v;
        if (n < N) v = *(const float4*)(X + (size_t)n * KK + col);
        else       v = make_float4(0.f, 0.f, 0.f, 0.f);
        if (pregelu) {
            v.x = gelu_exact(v.x); v.y = gelu_exact(v.y);
            v.z = gelu_exact(v.z); v.w = gelu_exact(v.w);
        }
        *(float4*)&xs[row][col] = v;
    }

    const int tr = tid >> 4, tc = tid & 15;
    const int tr4 = tr * 4, tcj = tc * 4;

    for (int c = 0; c < nchunks; c++) {
        float acc[4][4] = {};
        for (int ks = 0; ks < KK; ks += 64) {
            __syncthreads();
            // stage W rows ks..ks+63, cols c*64..c*64+63
            #pragma unroll
            for (int r = 0; r < 4; r++) {
                int f = tid + 256 * r;
                int row = f >> 4, col = (f & 15) * 4;
                *(float4*)&wsb[row][col] =
                    *(const float4*)(W + (size_t)(ks + row) * ldw + c * 64 + col);
            }
            __syncthreads();
            #pragma unroll
            for (int i = 0; i < 64; i += 4) {
                float4 A0 = *(const float4*)&xs[tr4 + 0][ks + i];
                float4 A1 = *(const float4*)&xs[tr4 + 1][ks + i];
                float4 A2 = *(const float4*)&xs[tr4 + 2][ks + i];
                float4 A3 = *(const float4*)&xs[tr4 + 3][ks + i];
                float4 W0 = *(const float4*)&wsb[i + 0][tcj];
                float4 W1 = *(const float4*)&wsb[i + 1][tcj];
                float4 W2 = *(const float4*)&wsb[i + 2][tcj];
                float4 W3 = *(const float4*)&wsb[i + 3][tcj];
#define ACCROW(m, AV)                                                              \
    acc[m][0] += AV.x * W0.x + AV.y * W1.x + AV.z * W2.x + AV.w * W3.x;            \
    acc[m][1] += AV.x * W0.y + AV.y * W1.y + AV.z * W2.y + AV.w * W3.y;            \
    acc[m][2] += AV.x * W0.z + AV.y * W1.z + AV.z * W2.z + AV.w * W3.z;            \
    acc[m][3] += AV.x * W0.w + AV.y * W1.w + AV.z * W2.w + AV.w * W3.w;
                ACCROW(0, A0) ACCROW(1, A1) ACCROW(2, A2) ACCROW(3, A3)
#undef ACCROW
            }
        }
        // epilogue
        const float* bp = bias + c * 64 + tcj;
        float b0 = bp[0], b1 = bp[1], b2 = bp[2], b3 = bp[3];
        if (mode == 0 || mode == 1) {
            float* base; int noff;
            if (mode == 0) {
                switch (c) {
                    case 0: base = o0; noff = 0;       break;
                    case 1: base = o1; noff = NA;      break;
                    case 2: base = o1; noff = NA + NP; break;
                    case 3: base = o2; noff = NA;      break;
                    default: base = o2; noff = NA + NP;
                }
            } else {
                switch (c) {
                    case 0: base = o0; noff = NP; break;
                    case 1: base = o1; noff = 0;  break;
                    default: base = o2; noff = 0;
                }
            }
            #pragma unroll
            for (int m = 0; m < 4; m++) {
                int n = nb + tr4 + m;
                if (n < N) {
                    float* p = base + (size_t)(noff + n) * HID + tcj;
                    p[0] = acc[m][0] + b0; p[1] = acc[m][1] + b1;
                    p[2] = acc[m][2] + b2; p[3] = acc[m][3] + b3;
                }
            }
        } else if (mode == 2) {
            float a = 1.0f / (1.0f + expf(-skip_ptr[0]));
            float oma = 1.0f - a;
            #pragma unroll
            for (int m = 0; m < 4; m++) {
                int n = nb + tr4 + m;
                if (n < N) {
                    size_t o = (size_t)n * HID + tcj;
                    o0[o + 0] = a * (acc[m][0] + b0) + oma * hres[o + 0];
                    o0[o + 1] = a * (acc[m][1] + b1) + oma * hres[o + 1];
                    o0[o + 2] = a * (acc[m][2] + b2) + oma * hres[o + 2];
                    o0[o + 3] = a * (acc[m][3] + b3) + oma * hres[o + 3];
                }
            }
        } else {
            #pragma unroll
            for (int m = 0; m < 4; m++) {
                int n = nb + tr4 + m;
                if (n < N) {
                    float* p = o0 + (size_t)n * HID + tcj;
                    p[0] = acc[m][0] + b0; p[1] = acc[m][1] + b1;
                    p[2] = acc[m][2] + b2; p[3] = acc[m][3] + b3;
                }
            }
        }
    }
}

// ---------------- fused attention: one wave per dst node, online softmax ----------------
__global__ __launch_bounds__(256) void attn_kernel(
    const float* Q, const float* __restrict__ Ks, const float* __restrict__ Vs,
    const float* __restrict__ p_rel, const int* __restrict__ row_ptr,
    const int* __restrict__ edge_src, float* attnout)
{
    int wid = threadIdx.x >> 6, lane = threadIdx.x & 63;
    int n = blockIdx.x * 4 + wid;
    if (n >= NTOT) return;
    int h = lane >> 4;
    float q = Q[(size_t)n * HID + lane];
    float pr0 = p_rel[h], pr1 = p_rel[4 + h], pr2 = p_rel[8 + h];
    int beg = row_ptr[n], end = row_ptr[n + 1];
    float m = -INFINITY, s = 0.0f, acc = 0.0f;
    for (int e = beg; e < end; e++) {
        int srcks = edge_src[e];
        size_t ro = (size_t)srcks * HID + lane;
        float k = Ks[ro];
        float v = Vs[ro];
        float prod = q * k;
        prod += __shfl_xor(prod, 1, 64);
        prod += __shfl_xor(prod, 2, 64);
        prod += __shfl_xor(prod, 4, 64);
        prod += __shfl_xor(prod, 8, 64);
        float pr = (srcks < NA) ? pr0 : ((srcks < NA + NP) ? pr1 : pr2);
        float alpha = prod * pr * 0.25f;   // 1/sqrt(16)
        float mn = fmaxf(m, alpha);
        float cc = expf(m - mn);
        float p  = expf(alpha - mn);
        s   = s * cc + p;
        acc = acc * cc + p * v;
        m = mn;
    }
    attnout[(size_t)n * HID + lane] = acc / (s + 1e-16f);
}

// ---------------- LN + gelu (one wave per node) ----------------
__global__ void ln_gelu_kernel(float* __restrict__ hbuf, const float* __restrict__ g,
                               const float* __restrict__ b, int base, int count) {
    int node = blockIdx.x * 4 + (threadIdx.x >> 6);
    int t = threadIdx.x & 63;
    if (node >= count) return;
    size_t off = (size_t)(base + node) * HID;
    float x = hbuf[off + t];
    float sum = x;
    #pragma unroll
    for (int o = 32; o > 0; o >>= 1) sum += __shfl_xor(sum, o, 64);
    float mean = sum * (1.0f / 64.0f);
    float d = x - mean;
    float vs = d * d;
    #pragma unroll
    for (int o = 32; o > 0; o >>= 1) vs += __shfl_xor(vs, o, 64);
    float var = vs * (1.0f / 64.0f);
    float y = d * rsqrtf(var + 1e-5f) * g[t] + b[t];
    hbuf[off + t] = gelu_exact(y);
}

extern "C" void kernel_launch(void* const* d_in, const int* in_sizes, int n_in,
                              void* d_out, int out_size, void* d_ws, size_t ws_size,
                              hipStream_t stream) {
    const float* x_paper  = (const float*)d_in[0];
    const float* x_author = (const float*)d_in[1];
    const int*   ei_ap    = (const int*)d_in[2];
    const int*   ei_pa    = (const int*)d_in[3];
    const int*   ei_pp    = (const int*)d_in[4];
    const float* W_in     = (const float*)d_in[5];
    const float* b_in     = (const float*)d_in[6];
    const float* W_kqv    = (const float*)d_in[7];
    const float* b_kqv    = (const float*)d_in[8];
    const float* W_krel   = (const float*)d_in[9];
    const float* W_vrel   = (const float*)d_in[10];
    const float* p_rel    = (const float*)d_in[11];
    const float* W_hout   = (const float*)d_in[12];
    const float* b_hout   = (const float*)d_in[13];
    const float* skip     = (const float*)d_in[14];
    const float* ln_g     = (const float*)d_in[15];
    const float* ln_b     = (const float*)d_in[16];
    const float* W_out    = (const float*)d_in[17];
    const float* b_out    = (const float*)d_in[18];
    float* out            = (float*)d_out;

    // ---- workspace layout (~211 MB) ----
    float* ws   = (float*)d_ws;
    float* hbuf = ws;                                   // NTOT*64
    float* Q    = hbuf + (size_t)NTOT * HID;            // NTOT*64 (attn output aliases Q)
    float* Ks   = Q    + (size_t)NTOT * HID;            // NSRC*64
    float* Vs   = Ks   + (size_t)NSRC * HID;            // NSRC*64
    float* Wfp  = Vs   + (size_t)NSRC * HID;            // 64*320
    float* bfp  = Wfp  + 64 * JP;                       // 320
    float* Wfa  = bfp  + JP;                            // 64*192
    float* bfa  = Wfa  + 64 * JA;                       // 192
    int* cnt      = (int*)(bfa + JA);                   // NTOT
    int* row_ptr  = cnt + NTOT;                         // NTOT+1 (pad to NTOT+16)
    int* cursor   = row_ptr + NTOT + 16;                // NTOT
    int* edge_src = cursor + NTOT;                      // ETOT
    int* csum     = edge_src + ETOT;                    // 1024
    int* coff     = csum + 1024;                        // 1024

    dim3 blk(256);
    const int EB = (ETOT + 255) / 256;

    // ---- CSR build (edges are layer-invariant) ----
    zero_int_kernel<<<256, blk, 0, stream>>>(cnt, NTOT);
    csr_count_kernel<<<EB, blk, 0, stream>>>(ei_ap, ei_pa, ei_pp, cnt);
    scan_chunk_sums<<<NCH, blk, 0, stream>>>(cnt, csum);
    scan_offsets<<<1, 1024, 0, stream>>>(csum, coff, NCH);
    scan_final<<<NCH, blk, 0, stream>>>(cnt, coff, row_ptr, cursor);
    csr_fill_kernel<<<EB, blk, 0, stream>>>(ei_ap, ei_pa, ei_pp, cursor, edge_src);

    // ---- input projection (K=128) ----
    gemm_rt<128><<<(NP + 63) / 64, blk, 0, stream>>>(
        x_paper, NP, W_in, b_in, HID, 1, 3, hbuf, nullptr, nullptr, nullptr, nullptr);
    gemm_rt<128><<<(NA + 63) / 64, blk, 0, stream>>>(
        x_author, NA, W_in + IN_DIM * HID, b_in + HID, HID, 1, 3,
        hbuf + (size_t)NP * HID, nullptr, nullptr, nullptr, nullptr);

    for (int l = 0; l < LAYERS; l++) {
        fuse_weights_kernel<<<(65 * JP + 65 * JA + 255) / 256, blk, 0, stream>>>(
            W_kqv + (size_t)l * 2 * HID * KQV, b_kqv + (size_t)l * 2 * KQV,
            W_krel + (size_t)l * 3 * NH * HD * HD, W_vrel + (size_t)l * 3 * NH * HD * HD,
            Wfp, bfp, Wfa, bfa);
        gemm_rt<64><<<(NP + 63) / 64, blk, 0, stream>>>(
            hbuf, NP, Wfp, bfp, JP, 5, 0, Q, Ks, Vs, nullptr, nullptr);
        gemm_rt<64><<<(NA + 63) / 64, blk, 0, stream>>>(
            hbuf + (size_t)NP * HID, NA, Wfa, bfa, JA, 3, 1, Q, Ks, Vs, nullptr, nullptr);
        attn_kernel<<<(NTOT + 3) / 4, blk, 0, stream>>>(
            Q, Ks, Vs, p_rel + l * 3 * NH, row_ptr, edge_src, Q);
        gemm_rt<64><<<(NP + 63) / 64, blk, 0, stream>>>(
            Q, NP, W_hout + (size_t)(l * 2 + 0) * HID * HID, b_hout + (l * 2 + 0) * HID,
            HID, 1, 2, hbuf, nullptr, nullptr, hbuf, skip + l * 2 + 0);
        gemm_rt<64><<<(NA + 63) / 64, blk, 0, stream>>>(
            Q + (size_t)NP * HID, NA,
            W_hout + (size_t)(l * 2 + 1) * HID * HID, b_hout + (l * 2 + 1) * HID,
            HID, 1, 2, hbuf + (size_t)NP * HID, nullptr, nullptr,
            hbuf + (size_t)NP * HID, skip + l * 2 + 1);
        ln_gelu_kernel<<<(NP + 3) / 4, blk, 0, stream>>>(
            hbuf, ln_g + (l * 2 + 0) * HID, ln_b + (l * 2 + 0) * HID, 0, NP);
        ln_gelu_kernel<<<(NA + 3) / 4, blk, 0, stream>>>(
            hbuf, ln_g + (l * 2 + 1) * HID, ln_b + (l * 2 + 1) * HID, NP, NA);
    }

    gemm_rt<64><<<(NP + 63) / 64, blk, 0, stream>>>(
        hbuf, NP, W_out, b_out, HID, 1, 3, out, nullptr, nullptr, nullptr, nullptr);
    gemm_rt<64><<<(NA + 63) / 64, blk, 0, stream>>>(
        hbuf + (size_t)NP * HID, NA, W_out + HID * HID, b_out + HID, HID, 1, 3,
        out + (size_t)NP * HID, nullptr, nullptr, nullptr, nullptr);
}